// Round 6
// baseline (120.092 us; speedup 1.0000x reference)
//
#include <hip/hip_runtime.h>

// NCN recurrence, 2 layers. B=4, N=4096, E=128, NK=4, ce=32, CACHE=32, m=128.
// 2048 independent [32 rows x 32 feats] subproblems per layer.
//
// R15: HALVE THE RCP COUNT (paired reciprocal). Issue model per wave-step:
//   VALU ~136 cyc (packed f32), trans ~256 cyc (16 exp2 + 16 rcp at 1/4
//   rate), LDS ~32 cyc -> trans pipe is the modeled bound. Replace the two
//   per-f32x2 rcp with ONE: r = rcp(den.x*den.y); 1/den.x = r*den.y;
//   1/den.y = r*den.x. den >= 1 (no underflow); clamp arg <= 63 so
//   den.x*den.y <= ~2^126 never overflows (tanh(63*ln2/2) == 1 in fp32, so
//   clamping is exact). Trans/step: 32 -> 24 (-25% on the bound pipe),
//   VALU +2 instr/q on the slack pipe. Accuracy cost ~2ulp -> ~1e-7 abs.
//
// Kept from R14: defused two dispatches (fused grid-barrier cost ~50us in
// agent-fence traffic, R12/R13); scaled-domain mid-state in d_ws; wave-
// autonomous groups; amdgpu_waves_per_eu(2,2) (2048 waves = 2/SIMD is all
// the parallelism the problem has).
//
// Per-layer core (R10): one wave64 = one (b,g,n) unit.
//   lane l: row r=l>>1, feat half h=l&1 (16 feats = 8 f32x2).
//   row-j broadcast: 16x ds_bpermute (imm-folded addr), no LDS/barriers.
//   pair reduce via DPP quad_perm; row-j Wj-dot via v_readlane (imm lane).
//   scaled domain: Xi=L1*xi, Ya=0.1*L1*xa, W pre-scaled by ln2;
//   tanh = 1 - 2/(exp2(arg)+1), arg = Xi + sim*Xj, clamp arg<=63.

namespace {
constexpr int kB = 4;
constexpr int kN = 4096;
constexpr int kE = 128;
constexpr int kCE = 32;          // E / NK
constexpr int kCache = 32;
constexpr int kM = kN / kCache;  // 128 groups per batch

constexpr float kL1    = 1.4426950408889634f;   // log2(e)
constexpr float kInvL1 = 0.6931471805599453f;   // ln(2)

typedef __attribute__((ext_vector_type(2))) float f32x2;

__device__ __forceinline__ f32x2 pk_fma(f32x2 a, f32x2 b, f32x2 c) {
    return __builtin_elementwise_fma(a, b, c);
}

// x + partner(l^1)'s x via DPP quad_perm [1,0,3,2] — no LDS roundtrip.
__device__ __forceinline__ float pair_sum(float x) {
    int sw = __builtin_amdgcn_update_dpp(0, __float_as_int(x),
                                         0xB1, 0xF, 0xF, true);
    return x + __int_as_float(sw);
}

// pull both halves of an f32x2 from lane (byte_addr >> 2)
__device__ __forceinline__ f32x2 bperm2(int byte_addr, f32x2 v) {
    f32x2 r;
    r.x = __int_as_float(
        __builtin_amdgcn_ds_bpermute(byte_addr, __float_as_int(v.x)));
    r.y = __int_as_float(
        __builtin_amdgcn_ds_bpermute(byte_addr, __float_as_int(v.y)));
    return r;
}
}  // namespace

// S: group stride (0 for stage 0, 1 for stage 1).
// IN_SCALED:  inputs already in scaled domain (Xi = L1*x, Ya = 0.1*L1*xa).
// OUT_SCALED: leave outputs in scaled domain (skip unscale).
template <int S, bool IN_SCALED, bool OUT_SCALED>
__global__ void __launch_bounds__(256)
__attribute__((amdgpu_waves_per_eu(2, 2)))
ncn_layer_kernel(const float* __restrict__ x_in,
                 const float* __restrict__ xa_in,
                 const float* __restrict__ Wl,   // this layer's 256 floats
                 float* __restrict__ x_out,
                 float* __restrict__ xa_out)
{
    const int t    = threadIdx.x;
    const int unit = blockIdx.x * 4 + (t >> 6);   // (b, g, n), 0..2047
    const int l    = t & 63;

    const int n = unit & 3;
    const int g = (unit >> 2) & (kM - 1);
    const int b = unit >> 9;

    const int h = l & 1;                        // feat half: [h*16, h*16+16)
    const int r = l >> 1;                       // row in group, 0..31

    // global row: ((g + r*S) % m) * CACHE + r
    const int gr = (((g + r * S) & (kM - 1)) << 5) + r;
    const size_t base = ((size_t)(b * kN + gr)) * kE + n * kCE + h * 16;

    // state (scaled domain) + weights (pre-scaled by ln2 -> dots = TRUE sim)
    f32x2 xi[8], ya[8], wi[8], wj[8];
    {
        const float4* xi4 = reinterpret_cast<const float4*>(x_in + base);
        const float4* xa4 = reinterpret_cast<const float4*>(xa_in + base);
        const float4* wi4 = reinterpret_cast<const float4*>(Wl + n * kCE + h * 16);
        const float4* wj4 = reinterpret_cast<const float4*>(Wl + kE + n * kCE + h * 16);
#pragma unroll
        for (int q4 = 0; q4 < 4; ++q4) {
            float4 v = xi4[q4];
            float4 a = xa4[q4];
            if constexpr (IN_SCALED) {
                xi[2 * q4 + 0] = f32x2{v.x, v.y};
                xi[2 * q4 + 1] = f32x2{v.z, v.w};
                ya[2 * q4 + 0] = f32x2{a.x, a.y};
                ya[2 * q4 + 1] = f32x2{a.z, a.w};
            } else {
                xi[2 * q4 + 0] = f32x2{v.x * kL1, v.y * kL1};
                xi[2 * q4 + 1] = f32x2{v.z * kL1, v.w * kL1};
                ya[2 * q4 + 0] = f32x2{a.x * (0.1f * kL1), a.y * (0.1f * kL1)};
                ya[2 * q4 + 1] = f32x2{a.z * (0.1f * kL1), a.w * (0.1f * kL1)};
            }
            float4 u = wi4[q4];
            wi[2 * q4 + 0] = f32x2{u.x * kInvL1, u.y * kInvL1};
            wi[2 * q4 + 1] = f32x2{u.z * kInvL1, u.w * kInvL1};
            float4 w2 = wj4[q4];
            wj[2 * q4 + 0] = f32x2{w2.x * kInvL1, w2.y * kInvL1};
            wj[2 * q4 + 1] = f32x2{w2.z * kInvL1, w2.w * kInvL1};
        }
    }

    const int v4h = h << 2;                     // bpermute byte base (lane*4)

    const f32x2 one  = {1.0f, 1.0f};
    const f32x2 c9   = {0.9f, 0.9f};
    const f32x2 cA   = {0.01f * kL1, 0.01f * kL1};     // + 0.01*L1
    const f32x2 cB   = {-0.02f * kL1, -0.02f * kL1};   // - 0.02*L1 * rc
    const f32x2 clmp = {63.0f, 63.0f};                 // overflow guard

#pragma unroll
    for (int j = 0; j < kCache; ++j) {
        // (1) pull row j's own-half feats from lanes 2j / 2j+1 (pre-update
        //     state: program order guarantees all lanes are at step j)
        const int addr = v4h + 8 * j;           // folds to offset imm
        f32x2 xj[8];
#pragma unroll
        for (int q = 0; q < 8; ++q) xj[q] = bperm2(addr, xi[q]);

        // (2) own-row dots over own 16 feats (true domain):
        //     a = xi_r . Wi   e = xi_r . Wj
        f32x2 a0 = xi[0] * wi[0], a1 = xi[1] * wi[1];
        f32x2 e0 = xi[0] * wj[0], e1 = xi[1] * wj[1];
        a0 = pk_fma(xi[2], wi[2], a0); a1 = pk_fma(xi[3], wi[3], a1);
        e0 = pk_fma(xi[2], wj[2], e0); e1 = pk_fma(xi[3], wj[3], e1);
        a0 = pk_fma(xi[4], wi[4], a0); a1 = pk_fma(xi[5], wi[5], a1);
        e0 = pk_fma(xi[4], wj[4], e0); e1 = pk_fma(xi[5], wj[5], e1);
        a0 = pk_fma(xi[6], wi[6], a0); a1 = pk_fma(xi[7], wi[7], a1);
        e0 = pk_fma(xi[6], wj[6], e0); e1 = pk_fma(xi[7], wj[7], e1);
        f32x2 av = a0 + a1, ev = e0 + e1;
        float a = av.x + av.y;
        float e = ev.x + ev.y;
        a = pair_sum(a);                        // full 32-feat row dot
        e = pair_sum(e);

        // (3) row j's Wj-dot: one readlane (lane 2j holds it), uniform scalar
        const float dj = __int_as_float(
            __builtin_amdgcn_readlane(__float_as_int(e), 2 * j));
        const float sim = a + dj;               // true sim for this row
        const f32x2 sv = {sim, sim};

        // (4) elementwise update in scaled domain; paired rcp (1 per f32x2)
#pragma unroll
        for (int q = 0; q < 8; ++q) {
            f32x2 arg = pk_fma(xj[q], sv, xi[q]);   // L1*(xi + sim*xj) = L1*2T
            arg = __builtin_elementwise_min(arg, clmp);  // exact: tanh==1 here
            f32x2 t2;
            t2.x = __builtin_amdgcn_exp2f(arg.x);
            t2.y = __builtin_amdgcn_exp2f(arg.y);
            f32x2 den = t2 + one;               // den >= 1, <= ~2^63
            // paired reciprocal: 1 rcp for both halves
            const float pr = den.x * den.y;     // <= ~2^126, finite
            const float ri = __builtin_amdgcn_rcpf(pr);
            f32x2 dsw = __builtin_shufflevector(den, den, 1, 0);
            f32x2 rc  = dsw * f32x2{ri, ri};    // {1/den.x, 1/den.y}
            // Ya' = 0.9*Ya + 0.01*L1 - 0.02*L1*rc   (Ya = 0.1*L1*xa)
            f32x2 yt = pk_fma(ya[q], c9, cA);
            ya[q] = pk_fma(rc, cB, yt);
            // Xi' = 0.9*Xi + Ya'
            xi[q] = pk_fma(xi[q], c9, ya[q]);
        }
    }

    // epilogue
    {
        float4* xo4 = reinterpret_cast<float4*>(x_out + base);
        float4* ao4 = reinterpret_cast<float4*>(xa_out + base);
#pragma unroll
        for (int q4 = 0; q4 < 4; ++q4) {
            f32x2 x0 = xi[2 * q4 + 0], x1 = xi[2 * q4 + 1];
            f32x2 a0 = ya[2 * q4 + 0], a1 = ya[2 * q4 + 1];
            if constexpr (!OUT_SCALED) {
                const f32x2 ivx = {kInvL1, kInvL1};
                const f32x2 iva = {10.0f * kInvL1, 10.0f * kInvL1};
                x0 = x0 * ivx; x1 = x1 * ivx;
                a0 = a0 * iva; a1 = a1 * iva;
            }
            float4 v; v.x = x0.x; v.y = x0.y; v.z = x1.x; v.w = x1.y;
            xo4[q4] = v;
            float4 w; w.x = a0.x; w.y = a0.y; w.z = a1.x; w.w = a1.y;
            ao4[q4] = w;
        }
    }
}

extern "C" void kernel_launch(void* const* d_in, const int* in_sizes, int n_in,
                              void* d_out, int out_size, void* d_ws, size_t ws_size,
                              hipStream_t stream) {
    const float* x  = (const float*)d_in[0];   // [B, N, E] fp32
    const float* xa = (const float*)d_in[1];   // [B, N, E] fp32
    const float* W  = (const float*)d_in[2];   // [2, 256] fp32

    const size_t plane = (size_t)kB * kN * kE;   // 2,097,152 floats (8 MiB)

    float* x_mid  = (float*)d_ws;                // scaled-domain mid-state
    float* xa_mid = x_mid + plane;               // (16 MiB total in ws)

    float* x_out  = (float*)d_out;               // final outputs
    float* xa_out = x_out + plane;

    const dim3 grid(kB * kM);   // 512 blocks x 4 waves = 2048 waves = 2/SIMD
    const dim3 block(256);

    // Layer 0 (stage 0): d_in -> ws, scaled domain   (pure, idempotent)
    ncn_layer_kernel<0, false, true><<<grid, block, 0, stream>>>(
        x, xa, W, x_mid, xa_mid);
    // Layer 1 (stage 1): ws -> d_out, unscaled       (pure, idempotent)
    ncn_layer_kernel<1, true, false><<<grid, block, 0, stream>>>(
        x_mid, xa_mid, W + 2 * kE, x_out, xa_out);
}

// Round 7
// 115.955 us; speedup vs baseline: 1.0357x; 1.0357x over previous
//
#include <hip/hip_runtime.h>

// NCN recurrence, 2 layers. B=4, N=4096, E=128, NK=4, ce=32, CACHE=32, m=128.
// 2048 independent [32 rows x 32 feats] subproblems per layer.
//
// R16: REVERT R15's paired-rcp (regressed 117.1 -> 120.1). The A/B result
// is the measurement: trading 8 trans/step for ~24 VALU/step LOST time ->
// v_exp_f32/v_rcp_f32 issue near VALU rate on gfx950 (not 1/4 rate); the
// kernel is VALU-issue/latency-bound. Keep the minimal-VALU form (R14,
// best measured 117.1us).
//
// Session state: fixed harness overhead ~75-85us (256MiB poison fill 44us
// + restores + gaps, confirmed in-region via R11's 247.5 = 176.4 kernel +
// 71 overhead); kernels ~32-40us vs ~28-30us composed floor (per layer:
// 2.5us load + 2.5us store @6.3TB/s + 6-8us recurrence issue/latency).
// R13/R14/R15 levers all |delta| <= 3us ~= noise.
//
// Structure (R14): defused two dispatches (fused grid-barrier cost ~50us,
// R12/R13); scaled-domain mid-state in d_ws; amdgpu_waves_per_eu(2,2)
// (2048 waves = 2/SIMD is all the parallelism the problem has).
//
// Per-layer core (R10): one wave64 = one (b,g,n) unit.
//   lane l: row r=l>>1, feat half h=l&1 (16 feats = 8 f32x2).
//   row-j broadcast: 16x ds_bpermute (imm-folded addr), no LDS/barriers.
//   pair reduce via DPP quad_perm; row-j Wj-dot via v_readlane (imm lane).
//   scaled domain: Xi=L1*xi, Ya=0.1*L1*xa, W pre-scaled by ln2;
//   tanh = 1 - 2/(exp2(arg)+1), arg = Xi + sim*Xj (exact +-1 at overflow).

namespace {
constexpr int kB = 4;
constexpr int kN = 4096;
constexpr int kE = 128;
constexpr int kCE = 32;          // E / NK
constexpr int kCache = 32;
constexpr int kM = kN / kCache;  // 128 groups per batch

constexpr float kL1    = 1.4426950408889634f;   // log2(e)
constexpr float kInvL1 = 0.6931471805599453f;   // ln(2)

typedef __attribute__((ext_vector_type(2))) float f32x2;

__device__ __forceinline__ f32x2 pk_fma(f32x2 a, f32x2 b, f32x2 c) {
    return __builtin_elementwise_fma(a, b, c);
}

// x + partner(l^1)'s x via DPP quad_perm [1,0,3,2] — no LDS roundtrip.
__device__ __forceinline__ float pair_sum(float x) {
    int sw = __builtin_amdgcn_update_dpp(0, __float_as_int(x),
                                         0xB1, 0xF, 0xF, true);
    return x + __int_as_float(sw);
}

// pull both halves of an f32x2 from lane (byte_addr >> 2)
__device__ __forceinline__ f32x2 bperm2(int byte_addr, f32x2 v) {
    f32x2 r;
    r.x = __int_as_float(
        __builtin_amdgcn_ds_bpermute(byte_addr, __float_as_int(v.x)));
    r.y = __int_as_float(
        __builtin_amdgcn_ds_bpermute(byte_addr, __float_as_int(v.y)));
    return r;
}
}  // namespace

// S: group stride (0 for stage 0, 1 for stage 1).
// IN_SCALED:  inputs already in scaled domain (Xi = L1*x, Ya = 0.1*L1*xa).
// OUT_SCALED: leave outputs in scaled domain (skip unscale).
template <int S, bool IN_SCALED, bool OUT_SCALED>
__global__ void __launch_bounds__(256)
__attribute__((amdgpu_waves_per_eu(2, 2)))
ncn_layer_kernel(const float* __restrict__ x_in,
                 const float* __restrict__ xa_in,
                 const float* __restrict__ Wl,   // this layer's 256 floats
                 float* __restrict__ x_out,
                 float* __restrict__ xa_out)
{
    const int t    = threadIdx.x;
    const int unit = blockIdx.x * 4 + (t >> 6);   // (b, g, n), 0..2047
    const int l    = t & 63;

    const int n = unit & 3;
    const int g = (unit >> 2) & (kM - 1);
    const int b = unit >> 9;

    const int h = l & 1;                        // feat half: [h*16, h*16+16)
    const int r = l >> 1;                       // row in group, 0..31

    // global row: ((g + r*S) % m) * CACHE + r
    const int gr = (((g + r * S) & (kM - 1)) << 5) + r;
    const size_t base = ((size_t)(b * kN + gr)) * kE + n * kCE + h * 16;

    // state (scaled domain) + weights (pre-scaled by ln2 -> dots = TRUE sim)
    f32x2 xi[8], ya[8], wi[8], wj[8];
    {
        const float4* xi4 = reinterpret_cast<const float4*>(x_in + base);
        const float4* xa4 = reinterpret_cast<const float4*>(xa_in + base);
        const float4* wi4 = reinterpret_cast<const float4*>(Wl + n * kCE + h * 16);
        const float4* wj4 = reinterpret_cast<const float4*>(Wl + kE + n * kCE + h * 16);
#pragma unroll
        for (int q4 = 0; q4 < 4; ++q4) {
            float4 v = xi4[q4];
            float4 a = xa4[q4];
            if constexpr (IN_SCALED) {
                xi[2 * q4 + 0] = f32x2{v.x, v.y};
                xi[2 * q4 + 1] = f32x2{v.z, v.w};
                ya[2 * q4 + 0] = f32x2{a.x, a.y};
                ya[2 * q4 + 1] = f32x2{a.z, a.w};
            } else {
                xi[2 * q4 + 0] = f32x2{v.x * kL1, v.y * kL1};
                xi[2 * q4 + 1] = f32x2{v.z * kL1, v.w * kL1};
                ya[2 * q4 + 0] = f32x2{a.x * (0.1f * kL1), a.y * (0.1f * kL1)};
                ya[2 * q4 + 1] = f32x2{a.z * (0.1f * kL1), a.w * (0.1f * kL1)};
            }
            float4 u = wi4[q4];
            wi[2 * q4 + 0] = f32x2{u.x * kInvL1, u.y * kInvL1};
            wi[2 * q4 + 1] = f32x2{u.z * kInvL1, u.w * kInvL1};
            float4 w2 = wj4[q4];
            wj[2 * q4 + 0] = f32x2{w2.x * kInvL1, w2.y * kInvL1};
            wj[2 * q4 + 1] = f32x2{w2.z * kInvL1, w2.w * kInvL1};
        }
    }

    const int v4h = h << 2;                     // bpermute byte base (lane*4)

    const f32x2 one = {1.0f, 1.0f};
    const f32x2 c9  = {0.9f, 0.9f};
    const f32x2 cA  = {0.01f * kL1, 0.01f * kL1};      // + 0.01*L1
    const f32x2 cB  = {-0.02f * kL1, -0.02f * kL1};    // - 0.02*L1 * rc

#pragma unroll
    for (int j = 0; j < kCache; ++j) {
        // (1) pull row j's own-half feats from lanes 2j / 2j+1 (pre-update
        //     state: program order guarantees all lanes are at step j)
        const int addr = v4h + 8 * j;           // folds to offset imm
        f32x2 xj[8];
#pragma unroll
        for (int q = 0; q < 8; ++q) xj[q] = bperm2(addr, xi[q]);

        // (2) own-row dots over own 16 feats (true domain):
        //     a = xi_r . Wi   e = xi_r . Wj
        f32x2 a0 = xi[0] * wi[0], a1 = xi[1] * wi[1];
        f32x2 e0 = xi[0] * wj[0], e1 = xi[1] * wj[1];
        a0 = pk_fma(xi[2], wi[2], a0); a1 = pk_fma(xi[3], wi[3], a1);
        e0 = pk_fma(xi[2], wj[2], e0); e1 = pk_fma(xi[3], wj[3], e1);
        a0 = pk_fma(xi[4], wi[4], a0); a1 = pk_fma(xi[5], wi[5], a1);
        e0 = pk_fma(xi[4], wj[4], e0); e1 = pk_fma(xi[5], wj[5], e1);
        a0 = pk_fma(xi[6], wi[6], a0); a1 = pk_fma(xi[7], wi[7], a1);
        e0 = pk_fma(xi[6], wj[6], e0); e1 = pk_fma(xi[7], wj[7], e1);
        f32x2 av = a0 + a1, ev = e0 + e1;
        float a = av.x + av.y;
        float e = ev.x + ev.y;
        a = pair_sum(a);                        // full 32-feat row dot
        e = pair_sum(e);

        // (3) row j's Wj-dot: one readlane (lane 2j holds it), uniform scalar
        const float dj = __int_as_float(
            __builtin_amdgcn_readlane(__float_as_int(e), 2 * j));
        const float sim = a + dj;               // true sim for this row
        const f32x2 sv = {sim, sim};

        // (4) elementwise update in scaled domain
#pragma unroll
        for (int q = 0; q < 8; ++q) {
            f32x2 arg = pk_fma(xj[q], sv, xi[q]);   // L1*(xi + sim*xj) = L1*2T
            f32x2 t2;
            t2.x = __builtin_amdgcn_exp2f(arg.x);
            t2.y = __builtin_amdgcn_exp2f(arg.y);
            f32x2 den = t2 + one;
            f32x2 rc;
            rc.x = __builtin_amdgcn_rcpf(den.x);
            rc.y = __builtin_amdgcn_rcpf(den.y);
            // Ya' = 0.9*Ya + 0.01*L1 - 0.02*L1*rc   (Ya = 0.1*L1*xa)
            f32x2 yt = pk_fma(ya[q], c9, cA);
            ya[q] = pk_fma(rc, cB, yt);
            // Xi' = 0.9*Xi + Ya'
            xi[q] = pk_fma(xi[q], c9, ya[q]);
        }
    }

    // epilogue
    {
        float4* xo4 = reinterpret_cast<float4*>(x_out + base);
        float4* ao4 = reinterpret_cast<float4*>(xa_out + base);
#pragma unroll
        for (int q4 = 0; q4 < 4; ++q4) {
            f32x2 x0 = xi[2 * q4 + 0], x1 = xi[2 * q4 + 1];
            f32x2 a0 = ya[2 * q4 + 0], a1 = ya[2 * q4 + 1];
            if constexpr (!OUT_SCALED) {
                const f32x2 ivx = {kInvL1, kInvL1};
                const f32x2 iva = {10.0f * kInvL1, 10.0f * kInvL1};
                x0 = x0 * ivx; x1 = x1 * ivx;
                a0 = a0 * iva; a1 = a1 * iva;
            }
            float4 v; v.x = x0.x; v.y = x0.y; v.z = x1.x; v.w = x1.y;
            xo4[q4] = v;
            float4 w; w.x = a0.x; w.y = a0.y; w.z = a1.x; w.w = a1.y;
            ao4[q4] = w;
        }
    }
}

extern "C" void kernel_launch(void* const* d_in, const int* in_sizes, int n_in,
                              void* d_out, int out_size, void* d_ws, size_t ws_size,
                              hipStream_t stream) {
    const float* x  = (const float*)d_in[0];   // [B, N, E] fp32
    const float* xa = (const float*)d_in[1];   // [B, N, E] fp32
    const float* W  = (const float*)d_in[2];   // [2, 256] fp32

    const size_t plane = (size_t)kB * kN * kE;   // 2,097,152 floats (8 MiB)

    float* x_mid  = (float*)d_ws;                // scaled-domain mid-state
    float* xa_mid = x_mid + plane;               // (16 MiB total in ws)

    float* x_out  = (float*)d_out;               // final outputs
    float* xa_out = x_out + plane;

    const dim3 grid(kB * kM);   // 512 blocks x 4 waves = 2048 waves = 2/SIMD
    const dim3 block(256);

    // Layer 0 (stage 0): d_in -> ws, scaled domain   (pure, idempotent)
    ncn_layer_kernel<0, false, true><<<grid, block, 0, stream>>>(
        x, xa, W, x_mid, xa_mid);
    // Layer 1 (stage 1): ws -> d_out, unscaled       (pure, idempotent)
    ncn_layer_kernel<1, true, false><<<grid, block, 0, stream>>>(
        x_mid, xa_mid, W + 2 * kE, x_out, xa_out);
}